// Round 10
// baseline (85.316 us; speedup 1.0000x reference)
//
#include <hip/hip_runtime.h>
#include <hip/hip_bf16.h>

// Problem constants (from reference): B=262144, D=256, S=16, C=10.
#define D_DIM 256
#define S_SYS 16
#define C_CLS 10
#define BLK   1024                 // 16 waves/block, 1 block/CU (LDS-capped)
                                   // NOTE: 1024-thread block => VGPR must stay <=128
#define GRID  256
#define CPB   128                  // samples per chunk (1024 threads / 8 lanes-per-sample)

// LDS W layout: u32 = 2 packed bf16 (dims d, d+1).
//   slot(s, c, q, v) = s*S_STR + c*C_STR + q*L_STR + v      (v = 0..15 real, 16..19 pad)
//   v = 2j + t  ->  weight u32 for dims  j*32 + q*4 + 2t .. +1
// Per-lane, per-class: 16 CONTIGUOUS u32 -> 4x ds_read_b128.
// Banks: lane q starts at (20q mod 32) = {0,20,8,28,16,4,24,12}; each 8-lane group
// covers all 32 banks exactly once per b128 -> uniform 8 words/bank per wave inst
// (throughput-optimal) for ANY mix of sids across groups (S_STR mod 32 = 4 only
// rotates the permutation).
#define L_STR 20
#define C_STR 160      // 8 * L_STR
#define S_STR 1604     // C_CLS * C_STR + 4

__device__ __forceinline__ void load_x(float4 xb[8], const float* __restrict__ x,
                                       long i, int n, int q) {
    const long r = (i < n) ? i : (long)(n - 1);           // clamp (store is masked)
    const float4* p = (const float4*)(x + r * D_DIM) + q; // dims j*32 + q*4 .. +3
    #pragma unroll
    for (int j = 0; j < 8; ++j) xb[j] = p[j * 8];
}

__device__ __forceinline__ int load_sid(const int* __restrict__ sid, long i, int n) {
    return sid[(i < n) ? i : (long)(n - 1)] & (S_SYS - 1);
}

// 8-lane-group all-reduce on the VALU pipe (DPP), NOT the LDS pipe.
// __shfl_xor lowers to ds_swizzle (LDS pipe) which co-limits against the W
// ds_read_b128 stream; DPP moves the reduction to the (underused) VALU pipe.
// xor1 = quad_perm[1,0,3,2]=0xB1; xor2 = quad_perm[2,3,0,1]=0x4E;
// xor"4"-within-8 = row_half_mirror (0x141): lane l <-> 7-l gives every lane
// the complement half's partial in ONE hop. Full sum lands in all 8 lanes.
__device__ __forceinline__ float dpp_reduce8(float v) {
    int t;
    t = __builtin_amdgcn_update_dpp(0, __float_as_int(v), 0xB1, 0xF, 0xF, true);
    v += __int_as_float(t);
    t = __builtin_amdgcn_update_dpp(0, __float_as_int(v), 0x4E, 0xF, 0xF, true);
    v += __int_as_float(t);
    t = __builtin_amdgcn_update_dpp(0, __float_as_int(v), 0x141, 0xF, 0xF, true);
    v += __int_as_float(t);
    return v;
}

__device__ __forceinline__ void step_compute(const float4 xb[8], long i, int n, int q, int s,
                                             const unsigned* __restrict__ Wl,
                                             const float2* __restrict__ bl2,
                                             float* __restrict__ out) {
    const unsigned* wp = Wl + (unsigned)s * S_STR + (unsigned)q * L_STR;

    float acc[C_CLS];
    #pragma unroll
    for (int c = 0; c < C_CLS; ++c) {
        float a = 0.f;
        #pragma unroll
        for (int k = 0; k < 4; ++k) {                     // quad k covers j = 2k, 2k+1
            const uint4 wv = *(const uint4*)&wp[c * C_STR + 4 * k];
            const float4 x0 = xb[2 * k];
            const float4 x1 = xb[2 * k + 1];
            a = fmaf(x0.x, __uint_as_float(wv.x << 16),
                 fmaf(x0.y, __uint_as_float(wv.x & 0xFFFF0000u),
                  fmaf(x0.z, __uint_as_float(wv.y << 16),
                   fmaf(x0.w, __uint_as_float(wv.y & 0xFFFF0000u),
                    fmaf(x1.x, __uint_as_float(wv.z << 16),
                     fmaf(x1.y, __uint_as_float(wv.z & 0xFFFF0000u),
                      fmaf(x1.z, __uint_as_float(wv.w << 16),
                       fmaf(x1.w, __uint_as_float(wv.w & 0xFFFF0000u), a))))))));
        }
        acc[c] = a;
    }

    // reduce each class across the 8-lane group (VALU/DPP); lane q keeps
    // classes 2q and 2q+1 (compile-time c, runtime compare -> no scratch)
    const int q2 = q * 2;
    float lo = 0.f, hi = 0.f;
    #pragma unroll
    for (int c = 0; c < C_CLS; ++c) {
        float r = dpp_reduce8(acc[c]);
        if (c == q2)     lo = r;
        if (c == q2 + 1) hi = r;
    }
    if ((i < n) && (q < 5)) {
        const float2 bb = bl2[s * 5 + q];
        *(float2*)(out + i * C_CLS + q2) = make_float2(lo + bb.x, hi + bb.y);
    }
}

__global__ __launch_bounds__(BLK) void mainf_k(const float* __restrict__ x,
                                               const int* __restrict__ sid,
                                               const float* __restrict__ W,
                                               const float* __restrict__ b,
                                               float* __restrict__ out, int n) {
    __shared__ unsigned Wl[S_SYS * S_STR];    // 102,656 B
    __shared__ float2   bl2[S_SYS * 5];       // bias pairs (2j, 2j+1): 640 B

    const int tid = threadIdx.x;
    const int nch = (n + CPB - 1) / CPB;
    const int cpb = (nch + (int)gridDim.x - 1) / (int)gridDim.x;  // chunks per block
    const int c0 = (int)blockIdx.x * cpb;
    const int c1 = (c0 + cpb < nch) ? (c0 + cpb) : nch;
    if (c0 >= c1) return;                     // whole block exits (before any sync)

    // ---- stage all 16 systems' W (f32 -> bf16 RN-even, packed pairs), permuted ----
    const float2* __restrict__ Wg = (const float2*)W;   // pair-index: sc*128 + j*16 + q*2 + t
    for (int u = tid; u < S_SYS * C_CLS * 8 * 16; u += BLK) {   // 20480 real slots
        const int v  = u & 15;
        const int q  = (u >> 4) & 7;
        const int sc = u >> 7;                 // s*10 + c
        const int j  = v >> 1, t = v & 1;
        const float2 f = Wg[(size_t)sc * 128 + j * 16 + q * 2 + t];
        unsigned lo = __float_as_uint(f.x);
        unsigned hi = __float_as_uint(f.y);
        lo = (lo + 0x7FFFu + ((lo >> 16) & 1u)) >> 16;  // RN-even bf16
        hi = (hi + 0x7FFFu + ((hi >> 16) & 1u)) >> 16;
        const int s = sc / C_CLS, c = sc - s * C_CLS;
        Wl[s * S_STR + c * C_STR + q * L_STR + v] = (hi << 16) | lo;
    }
    if (tid < S_SYS * 5) {
        const int s = tid / 5, j = tid - s * 5;
        bl2[tid] = make_float2(b[s * C_CLS + 2 * j], b[s * C_CLS + 2 * j + 1]);
    }
    __syncthreads();

    const int g = tid >> 3;                   // group (0..127) = sample within chunk
    const int q = tid & 7;                    // lane within group

    // ---- 2-deep pipeline; sid prefetched WITH x (keeps vmcnt queue pure-prefetch) ----
    float4 A[8], Bf[8];
    int ch = c0;
    long iA = (long)ch * CPB + g;
    load_x(A, x, iA, n, q);
    int sA = load_sid(sid, iA, n);
    while (true) {
        const int chB = ch + 1;
        const bool vB = (chB < c1);
        const long iB = (long)chB * CPB + g;
        int sB = 0;
        if (vB) { load_x(Bf, x, iB, n, q); sB = load_sid(sid, iB, n); }
        step_compute(A, iA, n, q, sA, Wl, bl2, out);
        if (!vB) break;

        const int chA2 = chB + 1;
        const bool vA = (chA2 < c1);
        const long iA2 = (long)chA2 * CPB + g;
        if (vA) { load_x(A, x, iA2, n, q); sA = load_sid(sid, iA2, n); }
        step_compute(Bf, iB, n, q, sB, Wl, bl2, out);
        if (!vA) break;
        ch = chA2; iA = iA2;
    }
}

extern "C" void kernel_launch(void* const* d_in, const int* in_sizes, int n_in,
                              void* d_out, int out_size, void* d_ws, size_t ws_size,
                              hipStream_t stream) {
    const float* x = (const float*)d_in[0];
    const int* sid = (const int*)d_in[1];
    const float* W = (const float*)d_in[2];
    const float* b = (const float*)d_in[3];
    float* out = (float*)d_out;
    const int n = in_sizes[1];   // B

    mainf_k<<<GRID, BLK, 0, stream>>>(x, sid, W, b, out, n);
}

// Round 12
// 57.988 us; speedup vs baseline: 1.4713x; 1.4713x over previous
//
#include <hip/hip_runtime.h>
#include <hip/hip_bf16.h>

// Problem constants (from reference): B=262144, D=256, S=16, C=10.
#define D_DIM 256
#define S_SYS 16
#define C_CLS 10
#define BLK   1024                 // 16 waves/block, 1 block/CU (LDS-capped)
                                   // NOTE: 1024-thread block => VGPR must stay <=128
#define GRID  256
#define CPB   128                  // samples per chunk (1024 threads / 8 lanes-per-sample)

// LDS W layout (UNCHANGED from R9 except f16 instead of bf16 payload):
//   u32 = 2 packed f16 (dims d, d+1)
//   slot(s, c, q, v) = s*S_STR + c*C_STR + q*L_STR + v   (v = 0..15 real, 16..19 pad)
//   v = 2j + t  ->  weight u32 for dims  j*32 + q*4 + 2t .. +1
// Per-lane, per-class: 16 CONTIGUOUS u32 -> 4x ds_read_b128; each 8-lane group's
// starts (20q mod 32) cover all 32 banks exactly once -> conflict-free.
//
// R11 fix: clang's cvt_pkrtz/fdot2 builtins use __fp16 ext_vector(2), not
// _Float16 ext_vector(2) -> typedef corrected (compile error only, no logic change).
#define L_STR 20
#define C_STR 160      // 8 * L_STR
#define S_STR 1604     // C_CLS * C_STR + 4

typedef __attribute__((ext_vector_type(2))) __fp16 half2v;

__device__ __forceinline__ half2v pack2(float x, float y) {
    return __builtin_amdgcn_cvt_pkrtz(x, y);     // v_cvt_pkrtz_f16_f32
}

__device__ __forceinline__ float fdot2(unsigned w, half2v xp, float c) {
#if __has_builtin(__builtin_amdgcn_fdot2)
    return __builtin_amdgcn_fdot2(__builtin_bit_cast(half2v, w), xp, c, false);
#else
    float d;
    unsigned xu = __builtin_bit_cast(unsigned, xp);
    asm("v_dot2_f32_f16 %0, %1, %2, %3" : "=v"(d) : "v"(w), "v"(xu), "v"(c));
    return d;
#endif
}

__device__ __forceinline__ void load_x(float4 xb[8], const float* __restrict__ x,
                                       long i, int n, int q) {
    const long r = (i < n) ? i : (long)(n - 1);           // clamp (store is masked)
    const float4* p = (const float4*)(x + r * D_DIM) + q; // dims j*32 + q*4 .. +3
    #pragma unroll
    for (int j = 0; j < 8; ++j) xb[j] = p[j * 8];
}

__device__ __forceinline__ int load_sid(const int* __restrict__ sid, long i, int n) {
    return sid[(i < n) ? i : (long)(n - 1)] & (S_SYS - 1);
}

__device__ __forceinline__ void step_compute(const float4 xb[8], long i, int n, int q, int s,
                                             const unsigned* __restrict__ Wl,
                                             const float* __restrict__ bl,
                                             float* __restrict__ out) {
    const unsigned* wp = Wl + (unsigned)s * S_STR + (unsigned)q * L_STR;

    // pack this sample's 32 dims once: xp[2j] = (x.j0, x.j1), xp[2j+1] = (x.j2, x.j3)
    half2v xp[16];
    #pragma unroll
    for (int j = 0; j < 8; ++j) {
        xp[2 * j]     = pack2(xb[j].x, xb[j].y);
        xp[2 * j + 1] = pack2(xb[j].z, xb[j].w);
    }

    float acc[C_CLS];
    #pragma unroll
    for (int c = 0; c < C_CLS; ++c) {
        float a = 0.f;
        #pragma unroll
        for (int k = 0; k < 4; ++k) {                     // uint4 = slots v=4k..4k+3
            const uint4 wv = *(const uint4*)&wp[c * C_STR + 4 * k];
            a = fdot2(wv.x, xp[4 * k + 0], a);
            a = fdot2(wv.y, xp[4 * k + 1], a);
            a = fdot2(wv.z, xp[4 * k + 2], a);
            a = fdot2(wv.w, xp[4 * k + 3], a);
        }
        acc[c] = a;
    }

    // all-reduce each class within the 8-lane group (xor 1,2,4 stay in-group)
    float v0 = 0.f, v1 = 0.f;
    #pragma unroll
    for (int c = 0; c < C_CLS; ++c) {
        float r = acc[c];
        r += __shfl_xor(r, 1);
        r += __shfl_xor(r, 2);
        r += __shfl_xor(r, 4);
        if (c == q)     v0 = r;   // compile-time c, runtime compare (no scratch)
        if (c == 8 + q) v1 = r;
    }
    if (i < n) {
        float* op = out + i * C_CLS;
        op[q] = v0 + bl[s * C_CLS + q];
        if (q < 2) op[8 + q] = v1 + bl[s * C_CLS + 8 + q];
    }
}

__global__ __launch_bounds__(BLK) void mainf_k(const float* __restrict__ x,
                                               const int* __restrict__ sid,
                                               const float* __restrict__ W,
                                               const float* __restrict__ b,
                                               float* __restrict__ out, int n) {
    __shared__ unsigned Wl[S_SYS * S_STR];    // 102,656 B
    __shared__ float    bl[S_SYS * C_CLS];    // 640 B

    const int tid = threadIdx.x;
    const int nch = (n + CPB - 1) / CPB;
    const int cpb = (nch + (int)gridDim.x - 1) / (int)gridDim.x;  // chunks per block
    const int c0 = (int)blockIdx.x * cpb;
    const int c1 = (c0 + cpb < nch) ? (c0 + cpb) : nch;
    if (c0 >= c1) return;                     // whole block exits (before any sync)

    // ---- stage all 16 systems' W (f32 -> packed f16 pairs, RTZ), permuted ----
    const float2* __restrict__ Wg = (const float2*)W;   // pair-index: sc*128 + j*16 + q*2 + t
    for (int u = tid; u < S_SYS * C_CLS * 8 * 16; u += BLK) {   // 20480 real slots
        const int v  = u & 15;
        const int q  = (u >> 4) & 7;
        const int sc = u >> 7;                 // s*10 + c
        const int j  = v >> 1, t = v & 1;
        const float2 f = Wg[(size_t)sc * 128 + j * 16 + q * 2 + t];
        const int s = sc / C_CLS, c = sc - s * C_CLS;
        Wl[s * S_STR + c * C_STR + q * L_STR + v] =
            __builtin_bit_cast(unsigned, pack2(f.x, f.y));
    }
    if (tid < S_SYS * C_CLS) bl[tid] = b[tid];
    __syncthreads();

    const int g = tid >> 3;                   // group (0..127) = sample within chunk
    const int q = tid & 7;                    // lane within group

    // ---- 2-deep pipeline; sid prefetched WITH x (keeps vmcnt queue pure-prefetch) ----
    float4 A[8], Bf[8];
    int ch = c0;
    long iA = (long)ch * CPB + g;
    load_x(A, x, iA, n, q);
    int sA = load_sid(sid, iA, n);
    while (true) {
        const int chB = ch + 1;
        const bool vB = (chB < c1);
        const long iB = (long)chB * CPB + g;
        int sB = 0;
        if (vB) { load_x(Bf, x, iB, n, q); sB = load_sid(sid, iB, n); }
        step_compute(A, iA, n, q, sA, Wl, bl, out);
        if (!vB) break;

        const int chA2 = chB + 1;
        const bool vA = (chA2 < c1);
        const long iA2 = (long)chA2 * CPB + g;
        if (vA) { load_x(A, x, iA2, n, q); sA = load_sid(sid, iA2, n); }
        step_compute(Bf, iB, n, q, sB, Wl, bl, out);
        if (!vA) break;
        ch = chA2; iA = iA2;
    }
}

extern "C" void kernel_launch(void* const* d_in, const int* in_sizes, int n_in,
                              void* d_out, int out_size, void* d_ws, size_t ws_size,
                              hipStream_t stream) {
    const float* x = (const float*)d_in[0];
    const int* sid = (const int*)d_in[1];
    const float* W = (const float*)d_in[2];
    const float* b = (const float*)d_in[3];
    float* out = (float*)d_out;
    const int n = in_sizes[1];   // B

    mainf_k<<<GRID, BLK, 0, stream>>>(x, sid, W, b, out, n);
}